// Round 1
// baseline (163.790 us; speedup 1.0000x reference)
//
#include <hip/hip_runtime.h>
#include <hip/hip_bf16.h>

typedef __attribute__((ext_vector_type(8))) short short8;
typedef __attribute__((ext_vector_type(4))) float f32x4;
typedef __attribute__((address_space(1))) const void gvoid_t;
typedef __attribute__((address_space(3))) void lvoid_t;

#define NB 4096   // B
#define DD 256    // D
#define TWOB 8192

__device__ __forceinline__ unsigned short f2bf(float f) {
  unsigned int u = __float_as_uint(f);
  u += 0x7fffu + ((u >> 16) & 1u);
  return (unsigned short)(u >> 16);
}
__device__ __forceinline__ float bf2f(unsigned short s) {
  return __uint_as_float(((unsigned int)s) << 16);
}

// ---------------- normalize: z_i/z_j -> bf16 zn (8192 x 256) ----------------
__global__ __launch_bounds__(256) void norm_kernel(const float* __restrict__ zi,
                                                   const float* __restrict__ zj,
                                                   unsigned short* __restrict__ znb) {
  int wave = threadIdx.x >> 6, lane = threadIdx.x & 63;
  int row = blockIdx.x * 4 + wave;
  const float* src = (row < NB) ? (zi + (size_t)row * DD) : (zj + (size_t)(row - NB) * DD);
  float4 v = ((const float4*)src)[lane];
  float ss = v.x * v.x + v.y * v.y + v.z * v.z + v.w * v.w;
#pragma unroll
  for (int m = 32; m >= 1; m >>= 1) ss += __shfl_xor(ss, m);
  float nrm = fmaxf(sqrtf(ss), 1e-8f);
  float s = 1.0f / nrm;
  ushort4 o;
  o.x = f2bf(v.x * s); o.y = f2bf(v.y * s); o.z = f2bf(v.z * s); o.w = f2bf(v.w * s);
  ((ushort4*)(znb + (size_t)row * DD))[lane] = o;
}

// ---------------- pos_i = <zn_i, zn_{i+B}> ----------------
__global__ __launch_bounds__(256) void pos_kernel(const unsigned short* __restrict__ znb,
                                                  float* __restrict__ pos) {
  int wave = threadIdx.x >> 6, lane = threadIdx.x & 63;
  int row = blockIdx.x * 4 + wave;
  ushort4 a = ((const ushort4*)(znb + (size_t)row * DD))[lane];
  ushort4 b = ((const ushort4*)(znb + (size_t)(row + NB) * DD))[lane];
  float d = bf2f(a.x) * bf2f(b.x) + bf2f(a.y) * bf2f(b.y) +
            bf2f(a.z) * bf2f(b.z) + bf2f(a.w) * bf2f(b.w);
#pragma unroll
  for (int m = 32; m >= 1; m >>= 1) d += __shfl_xor(d, m);
  if (lane == 0) pos[row] = d;
}

// ---------------- group sum vectors v_g[4][256] ----------------
__global__ __launch_bounds__(256) void gsum_kernel(const unsigned short* __restrict__ znb,
                                                   const int* __restrict__ sf,
                                                   float* __restrict__ vsum) {
  int d = threadIdx.x;
  int base = blockIdx.x * 128;
  float acc[4] = {0.f, 0.f, 0.f, 0.f};
  for (int r = 0; r < 128; ++r) {
    int row = base + r;
    int g = sf[row];
    float v = bf2f(znb[(size_t)row * DD + d]);
#pragma unroll
    for (int q = 0; q < 4; ++q) acc[q] += (g == q) ? v : 0.0f;
  }
#pragma unroll
  for (int q = 0; q < 4; ++q) unsafeAtomicAdd(&vsum[q * DD + d], acc[q]);
}

// ---------------- main fused GEMM + exp + row-sum ----------------
// S-tile 128x128 per block, K=256 in 8 chunks of BK=32, double-buffered LDS,
// global_load_lds width 16, XOR swizzle (pair-of-rows, 8 slots) so frag
// ds_read_b128 is 2-way bank aliased (free).
__global__ __launch_bounds__(256, 3) void den_kernel(const unsigned short* __restrict__ znb,
                                                     float* __restrict__ den) {
  __shared__ __align__(16) unsigned short As[2][4096];  // 128 rows x 32 k (8KB each)
  __shared__ __align__(16) unsigned short Bs[2][4096];
  const int tid = threadIdx.x;
  const int lane = tid & 63, wave = tid >> 6;
  const int rowbase = blockIdx.x * 128, colbase = blockIdx.y * 128;

  // staging decode: lane -> (row-in-16, k-chunk) with XOR swizzle baked into the
  // per-lane GLOBAL address (LDS dst is fixed wave base + lane*16).
  const int u = lane >> 3;            // pair-unit within issue (0..7)
  const int cp = (lane & 7) ^ u;      // (b<<2)|c after swizzle
  const int ri = 2 * u + (cp >> 2);   // row within 16-row issue
  const int kelem = (cp & 3) * 8;     // element offset within 32-elem k-tile

  // frag read: lane reads row (lane&15), k-chunk (lane>>4); same swizzle.
  const int slot = ((((lane & 1) << 2) | (lane >> 4)) ^ ((lane >> 1) & 7));
  const int fragoff = ((lane & 15) >> 1) * 128 + slot * 16;  // bytes in 8KB buf
  const int wrow = wave & 1, wcol = wave >> 1;

  f32x4 zero = {0.f, 0.f, 0.f, 0.f};
  f32x4 acc[4][4];
#pragma unroll
  for (int i = 0; i < 4; ++i)
#pragma unroll
    for (int j = 0; j < 4; ++j) acc[i][j] = zero;

  auto stage = [&](int kt, int buf) {
#pragma unroll
    for (int j = 0; j < 2; ++j) {
      int is = wave * 2 + j;  // issue 0..7, 16 rows each
      int grow = rowbase + is * 16 + ri;
      const unsigned short* gpa = znb + (size_t)grow * DD + kt * 32 + kelem;
      __builtin_amdgcn_global_load_lds((gvoid_t*)gpa, (lvoid_t*)&As[buf][is * 512], 16, 0, 0);
      int gcol = colbase + is * 16 + ri;
      const unsigned short* gpb = znb + (size_t)gcol * DD + kt * 32 + kelem;
      __builtin_amdgcn_global_load_lds((gvoid_t*)gpb, (lvoid_t*)&Bs[buf][is * 512], 16, 0, 0);
    }
  };

  stage(0, 0);
  __syncthreads();
#pragma unroll
  for (int kt = 0; kt < 8; ++kt) {
    if (kt < 7) stage(kt + 1, (kt + 1) & 1);
    const int buf = kt & 1;
    short8 af[4], bfr[4];
#pragma unroll
    for (int mi = 0; mi < 4; ++mi)
      af[mi] = *(const short8*)((const char*)&As[buf][0] + wrow * 4096 + mi * 1024 + fragoff);
#pragma unroll
    for (int ni = 0; ni < 4; ++ni)
      bfr[ni] = *(const short8*)((const char*)&Bs[buf][0] + wcol * 4096 + ni * 1024 + fragoff);
#pragma unroll
    for (int mi = 0; mi < 4; ++mi)
#pragma unroll
      for (int ni = 0; ni < 4; ++ni)
        acc[mi][ni] = __builtin_amdgcn_mfma_f32_16x16x32_bf16(af[mi], bfr[ni], acc[mi][ni], 0, 0, 0);
    __syncthreads();
  }

  // epilogue: exp(2*S) and row sums. C layout: col=lane&15, row=(lane>>4)*4+reg.
  float rsum[4][4];
#pragma unroll
  for (int mi = 0; mi < 4; ++mi)
#pragma unroll
    for (int r = 0; r < 4; ++r) rsum[mi][r] = 0.f;
#pragma unroll
  for (int mi = 0; mi < 4; ++mi)
#pragma unroll
    for (int ni = 0; ni < 4; ++ni)
#pragma unroll
      for (int r = 0; r < 4; ++r) rsum[mi][r] += __expf(2.0f * acc[mi][ni][r]);
#pragma unroll
  for (int m = 1; m < 16; m <<= 1)
#pragma unroll
    for (int mi = 0; mi < 4; ++mi)
#pragma unroll
      for (int r = 0; r < 4; ++r) rsum[mi][r] += __shfl_xor(rsum[mi][r], m);
  if ((lane & 15) == 0) {
    int h = lane >> 4;
#pragma unroll
    for (int mi = 0; mi < 4; ++mi)
#pragma unroll
      for (int r = 0; r < 4; ++r)
        unsafeAtomicAdd(&den[rowbase + wrow * 64 + mi * 16 + h * 4 + r], rsum[mi][r]);
  }
}

// ---------------- final scalar reduction ----------------
__global__ __launch_bounds__(256) void final_kernel(const float* __restrict__ den,
                                                    const float* __restrict__ pos,
                                                    const float* __restrict__ vsum,
                                                    const int* __restrict__ sf,
                                                    float* __restrict__ out) {
  __shared__ float red[256];
  __shared__ float gsq[4];
  __shared__ int cnt[4];
  int tid = threadIdx.x;
  if (tid < 4) { gsq[tid] = 0.f; cnt[tid] = 0; }
  __syncthreads();
  int lc[4] = {0, 0, 0, 0};
  for (int r = tid; r < NB; r += 256) {
    int g = sf[r];
#pragma unroll
    for (int q = 0; q < 4; ++q) lc[q] += (g == q) ? 1 : 0;
  }
#pragma unroll
  for (int q = 0; q < 4; ++q) atomicAdd(&cnt[q], lc[q]);
  float ga[4] = {0.f, 0.f, 0.f, 0.f};
  for (int i = tid; i < 4 * DD; i += 256) {
    float v = vsum[i];
    int g = i >> 8;
#pragma unroll
    for (int q = 0; q < 4; ++q) ga[q] += (g == q) ? v * v : 0.f;
  }
#pragma unroll
  for (int q = 0; q < 4; ++q) atomicAdd(&gsq[q], ga[q]);

  const float e2 = __expf(2.0f);
  float ls = 0.f;
  for (int i = tid; i < TWOB; i += 256) ls += logf(den[i] - e2);
  float ps = 0.f;
  for (int i = tid; i < NB; i += 256) ps += pos[i];

  red[tid] = ls;
  __syncthreads();
  for (int s = 128; s > 0; s >>= 1) { if (tid < s) red[tid] += red[tid + s]; __syncthreads(); }
  float lstot = red[0];
  __syncthreads();
  red[tid] = ps;
  __syncthreads();
  for (int s = 128; s > 0; s >>= 1) { if (tid < s) red[tid] += red[tid + s]; __syncthreads(); }
  float pstot = red[0];
  __syncthreads();

  if (tid == 0) {
    // sum over 2B entries of -pos/T = -(1/0.5)*2*sum(pos) = -4*pstot
    float contrastive = (lstot - 4.0f * pstot) / (float)TWOB;
    float fsum = 0.f;
    int uniq = 0;
#pragma unroll
    for (int q = 0; q < 4; ++q) {
      float c = (float)cnt[q];
      if (cnt[q] > 0) uniq++;
      if (cnt[q] > 1) fsum += gsq[q] / (c * (c - 1.0f));
    }
    out[0] = contrastive + 0.1f * (fsum / (uniq > 0 ? (float)uniq : 1.0f));
  }
}

extern "C" void kernel_launch(void* const* d_in, const int* in_sizes, int n_in,
                              void* d_out, int out_size, void* d_ws, size_t ws_size,
                              hipStream_t stream) {
  const float* zi = (const float*)d_in[0];
  const float* zj = (const float*)d_in[1];
  const int* sf = (const int*)d_in[2];
  float* out = (float*)d_out;
  char* ws = (char*)d_ws;
  float* den = (float*)ws;                      // 8192 f32
  float* vsum = den + TWOB;                     // 1024 f32
  float* pos = vsum + 1024;                     // 4096 f32
  unsigned short* znb = (unsigned short*)(ws + 65536);  // 8192x256 bf16 (4MB)

  hipMemsetAsync(ws, 0, (TWOB + 1024) * sizeof(float), stream);
  hipLaunchKernelGGL(norm_kernel, dim3(TWOB / 4), dim3(256), 0, stream, zi, zj, znb);
  hipLaunchKernelGGL(gsum_kernel, dim3(32), dim3(256), 0, stream, znb, sf, vsum);
  hipLaunchKernelGGL(pos_kernel, dim3(NB / 4), dim3(256), 0, stream, znb, pos);
  hipLaunchKernelGGL(den_kernel, dim3(64, 64), dim3(256), 0, stream, znb, den);
  hipLaunchKernelGGL(final_kernel, dim3(1), dim3(256), 0, stream, den, pos, vsum, sf, out);
}